// Round 11
// baseline (91.193 us; speedup 1.0000x reference)
//
#include <hip/hip_runtime.h>
#include <math.h>

#define TAU_F 0.02f
#define NB 64
#define NQ 32
#define NS 256
#define ND 128
#define MAXT 12          // max 32-row tiles per doc (sum padded <= 352 -> 11)
#define PERMSTRIDE 384   // MAXT*32
#define LROW 140         // LDS row stride in bf16 (128 + 12 pad: ~2-way banks)

typedef __bf16 bf16x4 __attribute__((ext_vector_type(4)));
typedef __bf16 bf16x8 __attribute__((ext_vector_type(8)));
typedef float f32x16 __attribute__((ext_vector_type(16)));

// workspace layout (bytes)
#define OFF_SIMOUT  0u          // 64*64*5*4 = 81920
#define OFF_RED     81920u      // counter @ +0, acc(float) @ +64 bytes

// ---------------------------------------------------------------------------
// Kernel 1: fused partition + staging + MFMA. 512 blocks = 64 docs x 8
// query-batches; 8 blocks of a doc share an XCD. Each wave owns 2 b's
// end-to-end (bfrag straight from qemb — R6-verified pattern).
// Per block: ballot-based modality partition of doc c (R6-verified, ~us),
// then T tiles staged demb->LDS row-major/coalesced (rows indirected via
// sperm; fp32->bf16 in flight; stride-140 padding), double-buffered (R9
// pipeline). 16 MFMA (32x32x16) per tile per wave; per-wave max epilogue.
// Block 0 zeroes the loss reduction cells (consumed only by kernel 2).
// ---------------------------------------------------------------------------
__global__ __launch_bounds__(256, 2) void
main_kernel(const float* __restrict__ qemb, const float* __restrict__ demb,
            const int* __restrict__ mod, const int* __restrict__ qmask,
            float* __restrict__ simout, int* __restrict__ red) {
    int blk = blockIdx.x;              // 0..511
    int xcd = blk & 7;
    int idx = blk >> 3;                // 0..63
    int c   = xcd * 8 + (idx & 7);     // doc; 8 blocks per doc share an XCD
    int bq  = idx >> 3;                // 0..7 query-batch
    int tid = threadIdx.x;
    int lane = tid & 63, wv = tid >> 6;
    int li32 = lane & 31, kh = lane >> 5;
    int b0 = bq * 8 + wv * 2;          // this wave's 2 b's

    if (blk == 0 && tid == 0) { red[0] = 0; ((float*)red)[16] = 0.f; }

    // ---- query fragments straight from qemb (R6-verified load pattern) ----
    // B-operand: lane holds q col n=li32, k = kc*16 + kh*8 + j
    bf16x8 bfrag[2][8];
#pragma unroll
    for (int bi = 0; bi < 2; ++bi) {
        const float* qb = qemb + ((size_t)(b0 + bi) * NQ + li32) * ND + kh * 8;
#pragma unroll
        for (int kc = 0; kc < 8; ++kc) {
            float4 a = *(const float4*)(qb + kc * 16);
            float4 b2 = *(const float4*)(qb + kc * 16 + 4);
            bf16x8 o;
            o[0] = (__bf16)a.x;  o[1] = (__bf16)a.y;  o[2] = (__bf16)a.z;  o[3] = (__bf16)a.w;
            o[4] = (__bf16)b2.x; o[5] = (__bf16)b2.y; o[6] = (__bf16)b2.z; o[7] = (__bf16)b2.w;
            bfrag[bi][kc] = o;
        }
    }

    // ---- ballot-based modality partition (R6-verified, absmax 0.0) ----
    __shared__ int sperm[PERMSTRIDE];
    __shared__ int stilemod[MAXT];
    __shared__ int wcnt[4][4];      // [wave][modality-1]
    __shared__ int firsts[4];
    __shared__ int sT;

    if (tid < 4) firsts[tid] = NS;
    __syncthreads();
    int m_tok = mod[c * NS + tid];
    unsigned long long mk1 = __ballot(m_tok == 1);
    unsigned long long mk2 = __ballot(m_tok == 2);
    unsigned long long mk3 = __ballot(m_tok == 3);
    unsigned long long mk4 = __ballot(m_tok == 4);
    if (lane == 0) {
        wcnt[wv][0] = __popcll(mk1); wcnt[wv][1] = __popcll(mk2);
        wcnt[wv][2] = __popcll(mk3); wcnt[wv][3] = __popcll(mk4);
    }
    if (m_tok) atomicMin(&firsts[m_tok - 1], tid);
    __syncthreads();

    int cnt1 = wcnt[0][0] + wcnt[1][0] + wcnt[2][0] + wcnt[3][0];
    int cnt2 = wcnt[0][1] + wcnt[1][1] + wcnt[2][1] + wcnt[3][1];
    int cnt3 = wcnt[0][2] + wcnt[1][2] + wcnt[2][2] + wcnt[3][2];
    int cnt4 = wcnt[0][3] + wcnt[1][3] + wcnt[2][3] + wcnt[3][3];
    int pad1 = (cnt1 + 31) & ~31, pad2 = (cnt2 + 31) & ~31;
    int pad3 = (cnt3 + 31) & ~31, pad4 = (cnt4 + 31) & ~31;
    int off1 = 0, off2 = pad1, off3 = off2 + pad2, off4 = off3 + pad3;
    int total = off4 + pad4;
    if (tid == 0) sT = total >> 5;

    if (m_tok) {
        unsigned long long mk = (m_tok == 1) ? mk1 : (m_tok == 2) ? mk2
                              : (m_tok == 3) ? mk3 : mk4;
        int off = (m_tok == 1) ? off1 : (m_tok == 2) ? off2
                : (m_tok == 3) ? off3 : off4;
        int rank = __popcll(mk & ((1ull << lane) - 1ull));
#pragma unroll
        for (int w = 0; w < 4; ++w)
            if (w < wv) rank += wcnt[w][m_tok - 1];
        sperm[off + rank] = tid;
    }
    // pad slots: duplicate the segment's first token (max-invariant)
    if (tid < 128) {
        int m = tid >> 5, p = tid & 31;
        int cm = (m == 0) ? cnt1 : (m == 1) ? cnt2 : (m == 2) ? cnt3 : cnt4;
        int pm = (m == 0) ? pad1 : (m == 1) ? pad2 : (m == 2) ? pad3 : pad4;
        int om = (m == 0) ? off1 : (m == 1) ? off2 : (m == 2) ? off3 : off4;
        int slot = cm + p;
        if (slot < pm) sperm[om + slot] = firsts[m];
    }
    if (tid < MAXT) {
        int t0 = tid * 32;
        int m = 4;
        if (t0 < off2) m = 1; else if (t0 < off3) m = 2; else if (t0 < off4) m = 3;
        stilemod[tid] = m;
    }
    __syncthreads();

    // ---- tile loop: coalesced demb->LDS staging + MFMA, double-buffered ----
    __shared__ __bf16 sbuf[2][32 * LROW];   // 2 x 8.75 KB
    int T = sT;
    const float* dbase = demb + (size_t)c * NS * ND;

    // stage tile 0: item idx: row=idx>>5 (via sperm), f4=idx&31 -> 512B/row coalesced
    {
#pragma unroll
        for (int i = 0; i < 4; ++i) {
            int id2 = tid + 256 * i;
            int row = id2 >> 5, f4 = id2 & 31;
            int srow = sperm[row];
            float4 v = *(const float4*)(dbase + (size_t)srow * ND + f4 * 4);
            bf16x4 o;
            o[0] = (__bf16)v.x; o[1] = (__bf16)v.y; o[2] = (__bf16)v.z; o[3] = (__bf16)v.w;
            *(bf16x4*)&sbuf[0][row * LROW + f4 * 4] = o;
        }
    }
    __syncthreads();

    float vmax[2][4];
#pragma unroll
    for (int bi = 0; bi < 2; ++bi)
#pragma unroll
        for (int m = 0; m < 4; ++m) vmax[bi][m] = -1e30f;

    int cur = 0;
    for (int t = 0; t < T; ++t) {
        // prefetch next tile into VGPRs (hidden behind MFMA)
        float4 pf[4];
        bool haspf = (t + 1 < T);
        if (haspf) {
#pragma unroll
            for (int i = 0; i < 4; ++i) {
                int id2 = tid + 256 * i;
                int row = id2 >> 5, f4 = id2 & 31;
                int srow = sperm[(t + 1) * 32 + row];
                pf[i] = *(const float4*)(dbase + (size_t)srow * ND + f4 * 4);
            }
        }

        int tm = stilemod[t];   // wave-uniform
        f32x16 acc0 = {0.f,0.f,0.f,0.f,0.f,0.f,0.f,0.f,0.f,0.f,0.f,0.f,0.f,0.f,0.f,0.f};
        f32x16 acc1 = acc0;
#pragma unroll
        for (int kc = 0; kc < 8; ++kc) {
            const __bf16* ap = &sbuf[cur][li32 * LROW + kc * 16 + kh * 8];
            bf16x4 lo = *(const bf16x4*)ap;
            bf16x4 hi = *(const bf16x4*)(ap + 4);
            bf16x8 af;
#pragma unroll
            for (int j = 0; j < 4; ++j) { af[j] = lo[j]; af[j + 4] = hi[j]; }
            acc0 = __builtin_amdgcn_mfma_f32_32x32x16_bf16(af, bfrag[0][kc], acc0, 0, 0, 0);
            acc1 = __builtin_amdgcn_mfma_f32_32x32x16_bf16(af, bfrag[1][kc], acc1, 0, 0, 0);
        }
        float v0 = acc0[0], v1 = acc1[0];
#pragma unroll
        for (int r = 1; r < 16; ++r) { v0 = fmaxf(v0, acc0[r]); v1 = fmaxf(v1, acc1[r]); }
        v0 = fmaxf(v0, __shfl_xor(v0, 32, 64));
        v1 = fmaxf(v1, __shfl_xor(v1, 32, 64));
        switch (tm) {
        case 1:  vmax[0][0] = fmaxf(vmax[0][0], v0); vmax[1][0] = fmaxf(vmax[1][0], v1); break;
        case 2:  vmax[0][1] = fmaxf(vmax[0][1], v0); vmax[1][1] = fmaxf(vmax[1][1], v1); break;
        case 3:  vmax[0][2] = fmaxf(vmax[0][2], v0); vmax[1][2] = fmaxf(vmax[1][2], v1); break;
        default: vmax[0][3] = fmaxf(vmax[0][3], v0); vmax[1][3] = fmaxf(vmax[1][3], v1); break;
        }

        if (haspf) {
#pragma unroll
            for (int i = 0; i < 4; ++i) {
                int id2 = tid + 256 * i;
                int row = id2 >> 5, f4 = id2 & 31;
                bf16x4 o;
                o[0] = (__bf16)pf[i].x; o[1] = (__bf16)pf[i].y;
                o[2] = (__bf16)pf[i].z; o[3] = (__bf16)pf[i].w;
                *(bf16x4*)&sbuf[cur ^ 1][row * LROW + f4 * 4] = o;
            }
        }
        __syncthreads();
        cur ^= 1;
    }

    // per-wave epilogue (wave owns its 2 b's — no cross-wave reduction)
    int q = lane & 31;
#pragma unroll
    for (int bi = 0; bi < 2; ++bi) {
        int b = b0 + bi;
        float m1 = vmax[bi][0], m2 = vmax[bi][1], m3 = vmax[bi][2], m4 = vmax[bi][3];
        float agg = fmaxf(fmaxf(m1, m2), fmaxf(m3, m4));
        float s0 = (qmask[b * NQ + q] != 0) ? agg : 0.f;
        float s1 = m1, s2 = m2, s3 = m3, s4 = m4;
#pragma unroll
        for (int off = 16; off >= 1; off >>= 1) {   // fold within 32-lane half
            s0 += __shfl_xor(s0, off, 64);
            s1 += __shfl_xor(s1, off, 64);
            s2 += __shfl_xor(s2, off, 64);
            s3 += __shfl_xor(s3, off, 64);
            s4 += __shfl_xor(s4, off, 64);
        }
        if (lane == 0) {
            float* o = simout + ((size_t)b * NB + c) * 5;   // UNNORMALIZED sums
            o[0] = s0; o[1] = s1; o[2] = s2; o[3] = s3; o[4] = s4;
        }
    }
}

// ---------------------------------------------------------------------------
// Kernel 2: loss, 64 blocks (one per row) — unchanged from R7/R9 (validated).
// ---------------------------------------------------------------------------
__global__ __launch_bounds__(256) void
loss_kernel(const float* __restrict__ simout, const int* __restrict__ qtypes,
            const int* __restrict__ qmask, int* __restrict__ red,
            float* __restrict__ out) {
    int r = blockIdx.x;
    int tid = threadIdx.x;
    int lane = tid & 63, wv = tid >> 6;

    __shared__ float sv[320];
    for (int i = tid; i < 320; i += 256) sv[i] = simout[(size_t)r * 320 + i];

    __shared__ int scnt;
    if (wv == 0) {
        int on = (lane < NQ) ? (qmask[r * NQ + lane] != 0) : 0;
        unsigned long long bal = __ballot(on);
        if (lane == 0) scnt = __popcll(bal);
    }
    __syncthreads();
    int cq = scnt;
    float scale = 1.0f / (TAU_F * (float)(cq > 0 ? cq : 1));
    int skip = r * 5;                      // the agg-sim diagonal slot

    __shared__ float wred[4];
    float mx = -1e30f;
    for (int i = tid; i < 320; i += 256)
        if (i != skip) mx = fmaxf(mx, sv[i] * scale);
#pragma unroll
    for (int off = 32; off >= 1; off >>= 1) mx = fmaxf(mx, __shfl_xor(mx, off, 64));
    if (lane == 0) wred[wv] = mx;
    __syncthreads();
    mx = fmaxf(fmaxf(wred[0], wred[1]), fmaxf(wred[2], wred[3]));

    float sum = 0.f;
    for (int i = tid; i < 320; i += 256)
        if (i != skip) sum += expf(sv[i] * scale - mx);
#pragma unroll
    for (int off = 32; off >= 1; off >>= 1) sum += __shfl_xor(sum, off, 64);
    __syncthreads();
    if (lane == 0) wred[wv] = sum;
    __syncthreads();

    if (tid == 0) {
        float tot = wred[0] + wred[1] + wred[2] + wred[3];
        float pos = sv[r * 5 + qtypes[r]] * scale;
        float lr = (logf(tot) + mx - pos) * (1.0f / NB);
        float* acc = (float*)red + 16;
        float ret = atomicAdd(acc, lr);                  // device-coherent
        int bump = 1 + (ret > 1e37f ? 1 : 0);            // data-dep: wait ret
        int old = atomicAdd(red, bump);
        if (old == NB - 1) {
            float v = atomicAdd(acc, 0.f);               // coherent read-back
            out[0] = v;
        }
    }
}

// ---------------------------------------------------------------------------
extern "C" void kernel_launch(void* const* d_in, const int* in_sizes, int n_in,
                              void* d_out, int out_size, void* d_ws, size_t ws_size,
                              hipStream_t stream) {
    const float* qemb   = (const float*)d_in[0];
    const float* demb   = (const float*)d_in[1];
    const int*   mod    = (const int*)d_in[2];
    const int*   qtypes = (const int*)d_in[3];
    const int*   qmask  = (const int*)d_in[4];

    char* ws = (char*)d_ws;
    float* simout = (float*)(ws + OFF_SIMOUT);
    int*   red    = (int*)(ws + OFF_RED);

    main_kernel<<<512, 256, 0, stream>>>(qemb, demb, mod, qmask, simout, red);
    loss_kernel<<<NB, 256, 0, stream>>>(simout, qtypes, qmask, red, (float*)d_out);
}